// Round 4
// baseline (1269.089 us; speedup 1.0000x reference)
//
#include <hip/hip_runtime.h>
#include <stdint.h>

#define NN 4096
#define DD 64
#define GCOL 16
#define CCH 16
#define TMAX 112
#define ROUNDS_FAST 15
#define ROUNDS_FB 32

typedef unsigned long long u64;
typedef unsigned int u32;

#define RESC 0xFFFFFFFFFFFFFFFEull
#define EMPTY (~0ull)

__device__ __forceinline__ u64 pk(float d, u32 idx) {
  return (((u64)__float_as_uint(d)) << 32) | (u64)idx;
}

__device__ __forceinline__ float distfly(const float* __restrict__ x,
                                         const float* __restrict__ y,
                                         float xxi, float yyj, int i, int j) {
  const float* xi = x + (size_t)i * DD;
  const float* yj = y + (size_t)j * DD;
  float dot = 0.f;
#pragma unroll
  for (int k = 0; k < DD; ++k) dot = fmaf(xi[k], yj[k], dot);
  float sq = (xxi + yyj) - 2.0f * dot;
  return sqrtf(fmaxf(sq, 0.f));
}

__global__ void k_init(const float* __restrict__ x, const float* __restrict__ y,
                       float* xx, float* yy, int* rm, int* cm, int* FR, int* Fcnt,
                       u64* rowbest, u64* colpart) {
  int i = blockIdx.x * blockDim.x + threadIdx.x;
  if (i < NN) {
    const float* xi = x + (size_t)i * DD;
    const float* yi = y + (size_t)i * DD;
    float sx = 0.f, sy = 0.f;
#pragma unroll
    for (int k = 0; k < DD; ++k) { sx = fmaf(xi[k], xi[k], sx); sy = fmaf(yi[k], yi[k], sy); }
    xx[i] = sx; yy[i] = sy;
    rm[i] = -1; cm[i] = -1; FR[i] = i;
    rowbest[i] = ~0ull;                      // forces full rescan round 1
#pragma unroll
    for (int g = 0; g < CCH; ++g) colpart[(size_t)g * NN + i] = RESC;
    if (i == 0) *Fcnt = NN;
  }
}

// C[i][j] = sqrt(max(xx[i]+yy[j]-2*dot, 0)), 64x64 tiles. (unchanged, proven)
__global__ void k_build(const float* __restrict__ x, const float* __restrict__ y,
                        const float* __restrict__ xx, const float* __restrict__ yy,
                        float* __restrict__ C) {
  __shared__ float xs[64][65];
  __shared__ float ys[64][65];
  int t = threadIdx.x;
  int bi = blockIdx.y * 64, bj = blockIdx.x * 64;
  for (int e = t; e < 64 * 64; e += 256) {
    int r = e >> 6, c = e & 63;
    xs[r][c] = x[(size_t)(bi + r) * DD + c];
    ys[r][c] = y[(size_t)(bj + r) * DD + c];
  }
  __syncthreads();
  int tx = t & 15, ty = t >> 4;
  float acc[4][4];
#pragma unroll
  for (int r = 0; r < 4; ++r)
#pragma unroll
    for (int c = 0; c < 4; ++c) acc[r][c] = 0.f;
#pragma unroll
  for (int k = 0; k < 64; ++k) {
    float a[4], b[4];
#pragma unroll
    for (int r = 0; r < 4; ++r) a[r] = xs[ty * 4 + r][k];
#pragma unroll
    for (int c = 0; c < 4; ++c) b[c] = ys[tx * 4 + c][k];
#pragma unroll
    for (int r = 0; r < 4; ++r)
#pragma unroll
      for (int c = 0; c < 4; ++c) acc[r][c] = fmaf(a[r], b[c], acc[r][c]);
  }
#pragma unroll
  for (int r = 0; r < 4; ++r) {
    int i = bi + ty * 4 + r;
    float xxi = xx[i];
    float4 v;
    float* vp = (float*)&v;
#pragma unroll
    for (int c = 0; c < 4; ++c) {
      int j = bj + tx * 4 + c;
      float sq = (xxi + yy[j]) - 2.0f * acc[r][c];
      vp[c] = sqrtf(fmaxf(sq, 0.f));
    }
    *(float4*)(C + (size_t)i * NN + bj + tx * 4) = v;
  }
}

// ---------- fast path: incremental row minima ----------
__global__ void k_rowpass3(const float* __restrict__ C, const int* __restrict__ rm,
                           const int* __restrict__ cm, u64* __restrict__ rowbest) {
  int i = blockIdx.x;
  if (rm[i] != -1) return;
  u64 e = rowbest[i];
  u32 jb = (u32)e;
  if (jb < NN && cm[jb] == -1) return;   // cached min col still free -> still the min
  int t = threadIdx.x;
  __shared__ u64 red[256];
  const float* Ci = C + (size_t)i * NN;
  u64 best = ~0ull;
  for (int j0 = t * 4; j0 < NN; j0 += 1024) {
    float4 v = *(const float4*)(Ci + j0);
    int4 m = *(const int4*)(cm + j0);
    const float* vp = (const float*)&v;
    const int* mp = (const int*)&m;
#pragma unroll
    for (int c = 0; c < 4; ++c) {
      if (mp[c] == -1) {
        u64 key = pk(vp[c], (u32)(j0 + c));
        if (key < best) best = key;
      }
    }
  }
  red[t] = best;
  __syncthreads();
  for (int s = 128; s > 0; s >>= 1) {
    if (t < s) { if (red[t + s] < red[t]) red[t] = red[t + s]; }
    __syncthreads();
  }
  if (t == 0) rowbest[i] = red[0];
}

// incremental column minima: 16 col-blocks x 16 row-chunks, 1 thread = (chunk, col)
__global__ void k_colpass4(const float* __restrict__ C, const int* __restrict__ rm,
                           const int* __restrict__ cm, u64* __restrict__ colpart) {
  int t = threadIdx.x;
  int j = blockIdx.x * 256 + t;
  int g = blockIdx.y;
  u64* slot = colpart + (size_t)g * NN + j;
  if (cm[j] != -1) return;               // matched col: slot never read again
  u64 e = *slot;
  if (e == EMPTY) return;                // no free rows in chunk; rows never un-match
  u32 io = (u32)e;
  if (io < NN && rm[io] == -1) return;   // cached min row still free -> still the min
  int i0 = g * 256, i1 = i0 + 256;
  u64 best = ~0ull;
  for (int i = i0; i < i1; ++i) {
    if (rm[i] != -1) continue;
    u64 key = pk(C[(size_t)i * NN + j], (u32)i);
    if (key < best) best = key;
  }
  *slot = best;
}

__global__ void k_accept3(const u64* __restrict__ colpart, const u64* __restrict__ rowbest,
                          int* rm, int* cm, int* Fcnt) {
  if (*Fcnt == 0) return;
  int j = blockIdx.x * 256 + threadIdx.x;
  if (cm[j] != -1) return;
  u64 best = ~0ull;
#pragma unroll
  for (int g = 0; g < CCH; ++g) {
    u64 v = colpart[(size_t)g * NN + j];
    if (v < best) best = v;
  }
  if (best == ~0ull) return;
  int i = (int)(u32)best;
  if ((u32)(rowbest[i] & 0xffffffffu) == (u32)j) {
    rm[i] = j; cm[j] = i;
    atomicSub(Fcnt, 1);
  }
}

// Endgame: compact free set; if F<=TMAX run exact greedy on static-LDS submatrix
// with per-row cached minima; else global sequential fallback. Exact greedy order
// preserved via key (cost<<24)|(i*NN+j) (i*NN+j fits exactly in 24 bits).
// All loops bounded: each iteration matches exactly one pair.
__global__ __launch_bounds__(256) void k_endgame(const float* __restrict__ C,
                                                 int* rm, int* cm, int* FRg) {
  __shared__ float Csub[TMAX * TMAX];       // 50176 B static
  __shared__ int sF, sG, sc_star, scnt;
  __shared__ int sFR[TMAX], sFC[TMAX];
  __shared__ u64 rkey[TMAX];
  __shared__ int rcol[TMAX];
  __shared__ int cfree[TMAX];
  __shared__ u64 wred[4];
  __shared__ u64 red[256];
  int t = threadIdx.x;
  if (t == 0) { sF = 0; sG = 0; }
  __syncthreads();
  for (int i = t; i < NN; i += 256)
    if (rm[i] == -1) { int p = atomicAdd(&sF, 1); if (p < TMAX) sFR[p] = i; }
  for (int j = t; j < NN; j += 256)
    if (cm[j] == -1) { int p = atomicAdd(&sG, 1); if (p < TMAX) sFC[p] = j; }
  __syncthreads();
  int F = sF;
  if (F == 0) return;
  if (F <= TMAX) {
    for (int r = (t >> 6); r < F; r += 4) {
      const float* Ci = C + (size_t)sFR[r] * NN;
      for (int c = (t & 63); c < F; c += 64) Csub[r * F + c] = Ci[sFC[c]];
    }
    for (int c = t; c < F; c += 256) cfree[c] = 1;
    __syncthreads();
    for (int r = t; r < F; r += 256) {
      const float* row = Csub + r * F;
      u64 bk = ~0ull; int bc = 0; int ig = sFR[r];
      for (int c = 0; c < F; ++c) {
        u64 k = (((u64)__float_as_uint(row[c])) << 24) | (u32)(ig * NN + sFC[c]);
        if (k < bk) { bk = k; bc = c; }
      }
      rkey[r] = bk; rcol[r] = bc;
    }
    __syncthreads();
    for (int it = 0; it < F; ++it) {
      u64 kb = ~0ull;
      if (t < F && rkey[t] != ~0ull) kb = (rkey[t] << 8) | (u64)(u32)t;
      for (int s = 32; s > 0; s >>= 1) {
        u64 o = __shfl_down(kb, s, 64);
        if (o < kb) kb = o;
      }
      if ((t & 63) == 0) wred[t >> 6] = kb;
      __syncthreads();
      if (t == 0) {
        u64 b = wred[0];
#pragma unroll
        for (int wv = 1; wv < 4; ++wv) if (wred[wv] < b) b = wred[wv];
        int rstar = (int)(b & 255);
        if (rstar >= F) rstar = 0;            // defensive clamp (unreachable)
        int cstar = rcol[rstar];
        sc_star = cstar;
        int i = sFR[rstar], j = sFC[cstar];
        rm[i] = j; cm[j] = i;
        rkey[rstar] = ~0ull; cfree[cstar] = 0;
      }
      __syncthreads();
      int cs = sc_star;
      for (int r = t; r < F; r += 256) {
        if (rkey[r] != ~0ull && rcol[r] == cs) {
          const float* row = Csub + r * F;
          u64 bk = ~0ull; int bc = 0; int ig = sFR[r];
          for (int c = 0; c < F; ++c) {
            if (!cfree[c]) continue;
            u64 k = (((u64)__float_as_uint(row[c])) << 24) | (u32)(ig * NN + sFC[c]);
            if (k < bk) { bk = k; bc = c; }
          }
          rkey[r] = bk; rcol[r] = bc;
        }
      }
      __syncthreads();
    }
  } else {
    for (int it = 0; it < NN; ++it) {       // bounded: one match per iteration
      if (t == 0) scnt = 0;
      __syncthreads();
      for (int i = t; i < NN; i += 256)
        if (rm[i] == -1) { int p = atomicAdd(&scnt, 1); FRg[p] = i; }
      __syncthreads();
      int Fa = scnt;
      if (Fa == 0) break;
      u64 best = ~0ull;
      int total = Fa * NN;
      for (int idx = t; idx < total; idx += 256) {
        int b = idx >> 12, j = idx & 4095;
        if (cm[j] != -1) continue;
        int i = FRg[b];
        u64 key = pk(C[(size_t)i * NN + j], (u32)(i * NN + j));
        if (key < best) best = key;
      }
      red[t] = best;
      __syncthreads();
      for (int s = 128; s > 0; s >>= 1) {
        if (t < s) { if (red[t + s] < red[t]) red[t] = red[t + s]; }
        __syncthreads();
      }
      if (t == 0) {
        u32 lo = (u32)red[0];
        rm[lo >> 12] = lo & 4095; cm[lo & 4095] = lo >> 12;
      }
      __syncthreads();
    }
  }
}

// ---------- fallback path (no C in workspace) — unchanged, proven ----------
template <bool USEC>
__global__ void k_rowpass(const float* __restrict__ C,
                          const float* __restrict__ x, const float* __restrict__ y,
                          const float* __restrict__ xx, const float* __restrict__ yy,
                          const int* __restrict__ cm, const int* __restrict__ FR,
                          const int* __restrict__ Fcnt, u64* __restrict__ rowbest) {
  int b = blockIdx.x;
  if (b >= *Fcnt) return;
  int i = FR[b];
  __shared__ float xsh[DD];
  __shared__ u64 red[256];
  int t = threadIdx.x;
  if (!USEC) { if (t < DD) xsh[t] = x[(size_t)i * DD + t]; }
  __syncthreads();
  float xxi = xx[i];
  u64 best = ~0ull;
  for (int j = t; j < NN; j += 256) {
    if (cm[j] != -1) continue;
    float d;
    if (USEC) {
      d = C[(size_t)i * NN + j];
    } else {
      const float* yj = y + (size_t)j * DD;
      float dot = 0.f;
#pragma unroll
      for (int k = 0; k < DD; ++k) dot = fmaf(xsh[k], yj[k], dot);
      float sq = (xxi + yy[j]) - 2.0f * dot;
      d = sqrtf(fmaxf(sq, 0.f));
    }
    u64 key = pk(d, (u32)j);
    if (key < best) best = key;
  }
  red[t] = best;
  __syncthreads();
  for (int s = 128; s > 0; s >>= 1) {
    if (t < s) { if (red[t + s] < red[t]) red[t] = red[t + s]; }
    __syncthreads();
  }
  if (t == 0) rowbest[i] = red[0];
}

template <bool USEC>
__global__ void k_colpass(const float* __restrict__ C,
                          const float* __restrict__ x, const float* __restrict__ y,
                          const float* __restrict__ xx, const float* __restrict__ yy,
                          const int* __restrict__ cm, const int* __restrict__ FR,
                          const int* __restrict__ Fcnt, u64* __restrict__ colpart) {
  int t = threadIdx.x;
  int j = blockIdx.x * 256 + t;
  int g = blockIdx.y;
  int F = *Fcnt;
  if (F == 0) return;
  int b0 = (g * F) / GCOL, b1 = ((g + 1) * F) / GCOL;
  u64 best = ~0ull;
  if (cm[j] == -1) {
    float yyj = yy[j];
    if (USEC) {
      for (int b = b0; b < b1; ++b) {
        int i = FR[b];
        u64 key = pk(C[(size_t)i * NN + j], (u32)i);
        if (key < best) best = key;
      }
    } else {
      float4 yr[16];
      const float4* yj4 = (const float4*)(y + (size_t)j * DD);
#pragma unroll
      for (int q = 0; q < 16; ++q) yr[q] = yj4[q];
      for (int b = b0; b < b1; ++b) {
        int i = FR[b];
        const float4* xi4 = (const float4*)(x + (size_t)i * DD);
        float dot = 0.f;
#pragma unroll
        for (int q = 0; q < 16; ++q) {
          float4 a = xi4[q], bb = yr[q];
          dot = fmaf(a.x, bb.x, dot); dot = fmaf(a.y, bb.y, dot);
          dot = fmaf(a.z, bb.z, dot); dot = fmaf(a.w, bb.w, dot);
        }
        float sq = (xx[i] + yyj) - 2.0f * dot;
        float d = sqrtf(fmaxf(sq, 0.f));
        u64 key = pk(d, (u32)i);
        if (key < best) best = key;
      }
    }
  }
  colpart[(size_t)g * NN + j] = best;
}

__global__ void k_accept(const u64* __restrict__ colpart, const u64* __restrict__ rowbest,
                         int* rm, int* cm, int* FR, int* Fcnt) {
  __shared__ int scnt;
  int t = threadIdx.x;
  if (*Fcnt == 0) return;
  for (int j = t; j < NN; j += 1024) {
    if (cm[j] != -1) continue;
    u64 best = ~0ull;
#pragma unroll
    for (int g = 0; g < GCOL; ++g) {
      u64 v = colpart[(size_t)g * NN + j];
      if (v < best) best = v;
    }
    if (best == ~0ull) continue;
    int i = (int)(u32)best;
    if ((u32)(rowbest[i] & 0xffffffffu) == (u32)j) { rm[i] = j; cm[j] = i; }
  }
  __syncthreads();
  if (t == 0) scnt = 0;
  __syncthreads();
  for (int i = t; i < NN; i += 1024)
    if (rm[i] == -1) { int p = atomicAdd(&scnt, 1); FR[p] = i; }
  __syncthreads();
  if (t == 0) *Fcnt = scnt;
}

template <bool USEC>
__global__ void k_cleanup(const float* __restrict__ C,
                          const float* __restrict__ x, const float* __restrict__ y,
                          const float* __restrict__ xx, const float* __restrict__ yy,
                          int* rm, int* cm, int* FR) {
  __shared__ int scnt;
  __shared__ u64 red[1024];
  int t = threadIdx.x;
  for (int it = 0; it < NN; ++it) {         // bounded: one match per iteration
    if (t == 0) scnt = 0;
    __syncthreads();
    for (int i = t; i < NN; i += 1024)
      if (rm[i] == -1) { int p = atomicAdd(&scnt, 1); FR[p] = i; }
    __syncthreads();
    int F = scnt;
    if (F == 0) break;
    u64 best = ~0ull;
    int total = F * NN;
    for (int idx = t; idx < total; idx += 1024) {
      int b = idx >> 12;
      int j = idx & 4095;
      if (cm[j] != -1) continue;
      int i = FR[b];
      float d;
      if (USEC) d = C[(size_t)i * NN + j];
      else d = distfly(x, y, xx[i], yy[j], i, j);
      u64 key = pk(d, (u32)(i * NN + j));
      if (key < best) best = key;
    }
    red[t] = best;
    __syncthreads();
    for (int s = 512; s > 0; s >>= 1) {
      if (t < s) { if (red[t + s] < red[t]) red[t] = red[t + s]; }
      __syncthreads();
    }
    if (t == 0) {
      u32 lo = (u32)red[0];
      int i = lo >> 12, j = lo & 4095;
      rm[i] = j; cm[j] = i;
    }
    __syncthreads();
  }
}

extern "C" void kernel_launch(void* const* d_in, const int* in_sizes, int n_in,
                              void* d_out, int out_size, void* d_ws, size_t ws_size,
                              hipStream_t stream) {
  const float* x = (const float*)d_in[0];
  const float* y = (const float*)d_in[1];
  int* cm = (int*)d_out;

  char* w = (char*)d_ws;
  float* xx = (float*)(w + 0);
  float* yy = (float*)(w + 16384);
  int* rm = (int*)(w + 32768);
  int* FR = (int*)(w + 49152);
  int* Fcnt = (int*)(w + 65536);
  u64* rowbest = (u64*)(w + 65664);
  u64* colpart = (u64*)(w + 98432);   // 16 x 4096 x 8 = 512 KB, ends 622720
  float* C = (float*)(w + 1048576);

  size_t need = 1048576 + (size_t)NN * NN * 4;
  bool usec = ws_size >= need;

  k_init<<<dim3(16), 256, 0, stream>>>(x, y, xx, yy, rm, cm, FR, Fcnt, rowbest, colpart);
  if (usec) {
    k_build<<<dim3(64, 64), 256, 0, stream>>>(x, y, xx, yy, C);
    for (int r = 0; r < ROUNDS_FAST; ++r) {
      k_rowpass3<<<dim3(NN), 256, 0, stream>>>(C, rm, cm, rowbest);
      k_colpass4<<<dim3(16, CCH), 256, 0, stream>>>(C, rm, cm, colpart);
      k_accept3<<<dim3(16), 256, 0, stream>>>(colpart, rowbest, rm, cm, Fcnt);
    }
    k_endgame<<<dim3(1), 256, 0, stream>>>(C, rm, cm, FR);
  } else {
    for (int r = 0; r < ROUNDS_FB; ++r) {
      k_rowpass<false><<<dim3(NN), 256, 0, stream>>>(nullptr, x, y, xx, yy, cm, FR, Fcnt, rowbest);
      k_colpass<false><<<dim3(16, GCOL), 256, 0, stream>>>(nullptr, x, y, xx, yy, cm, FR, Fcnt, colpart);
      k_accept<<<dim3(1), 1024, 0, stream>>>(colpart, rowbest, rm, cm, FR, Fcnt);
    }
    k_cleanup<false><<<dim3(1), 1024, 0, stream>>>(nullptr, x, y, xx, yy, rm, cm, FR);
  }
}

// Round 5
// 672.347 us; speedup vs baseline: 1.8875x; 1.8875x over previous
//
#include <hip/hip_runtime.h>
#include <stdint.h>

#define NN 4096
#define DD 64
#define GCOL 16
#define CCH 16
#define TMAX 112
#define ROUNDS_FAST 22
#define ROUNDS_FB 32

typedef unsigned long long u64;
typedef unsigned int u32;

#define RESC 0xFFFFFFFFFFFFFFFEull
#define EMPTY (~0ull)

__device__ __forceinline__ u64 pk(float d, u32 idx) {
  return (((u64)__float_as_uint(d)) << 32) | (u64)idx;
}

__device__ __forceinline__ float distfly(const float* __restrict__ x,
                                         const float* __restrict__ y,
                                         float xxi, float yyj, int i, int j) {
  const float* xi = x + (size_t)i * DD;
  const float* yj = y + (size_t)j * DD;
  float dot = 0.f;
#pragma unroll
  for (int k = 0; k < DD; ++k) dot = fmaf(xi[k], yj[k], dot);
  float sq = (xxi + yyj) - 2.0f * dot;
  return sqrtf(fmaxf(sq, 0.f));
}

__global__ void k_init(const float* __restrict__ x, const float* __restrict__ y,
                       float* xx, float* yy, int* rm, int* cm, int* FR, int* Fcnt,
                       u64* rowbest, u64* colpart) {
  int i = blockIdx.x * blockDim.x + threadIdx.x;
  if (i < NN) {
    const float* xi = x + (size_t)i * DD;
    const float* yi = y + (size_t)i * DD;
    float sx = 0.f, sy = 0.f;
#pragma unroll
    for (int k = 0; k < DD; ++k) { sx = fmaf(xi[k], xi[k], sx); sy = fmaf(yi[k], yi[k], sy); }
    xx[i] = sx; yy[i] = sy;
    rm[i] = -1; cm[i] = -1; FR[i] = i;
    rowbest[i] = ~0ull;                      // forces full rescan round 1
#pragma unroll
    for (int g = 0; g < CCH; ++g) colpart[(size_t)g * NN + i] = RESC;
    if (i == 0) *Fcnt = NN;
  }
}

// C[i][j] = sqrt(max(xx[i]+yy[j]-2*dot, 0)), 64x64 tiles. (unchanged, proven)
__global__ void k_build(const float* __restrict__ x, const float* __restrict__ y,
                        const float* __restrict__ xx, const float* __restrict__ yy,
                        float* __restrict__ C) {
  __shared__ float xs[64][65];
  __shared__ float ys[64][65];
  int t = threadIdx.x;
  int bi = blockIdx.y * 64, bj = blockIdx.x * 64;
  for (int e = t; e < 64 * 64; e += 256) {
    int r = e >> 6, c = e & 63;
    xs[r][c] = x[(size_t)(bi + r) * DD + c];
    ys[r][c] = y[(size_t)(bj + r) * DD + c];
  }
  __syncthreads();
  int tx = t & 15, ty = t >> 4;
  float acc[4][4];
#pragma unroll
  for (int r = 0; r < 4; ++r)
#pragma unroll
    for (int c = 0; c < 4; ++c) acc[r][c] = 0.f;
#pragma unroll
  for (int k = 0; k < 64; ++k) {
    float a[4], b[4];
#pragma unroll
    for (int r = 0; r < 4; ++r) a[r] = xs[ty * 4 + r][k];
#pragma unroll
    for (int c = 0; c < 4; ++c) b[c] = ys[tx * 4 + c][k];
#pragma unroll
    for (int r = 0; r < 4; ++r)
#pragma unroll
      for (int c = 0; c < 4; ++c) acc[r][c] = fmaf(a[r], b[c], acc[r][c]);
  }
#pragma unroll
  for (int r = 0; r < 4; ++r) {
    int i = bi + ty * 4 + r;
    float xxi = xx[i];
    float4 v;
    float* vp = (float*)&v;
#pragma unroll
    for (int c = 0; c < 4; ++c) {
      int j = bj + tx * 4 + c;
      float sq = (xxi + yy[j]) - 2.0f * acc[r][c];
      vp[c] = sqrtf(fmaxf(sq, 0.f));
    }
    *(float4*)(C + (size_t)i * NN + bj + tx * 4) = v;
  }
}

// Fused round: blocks [0,NN) = incremental row minima; blocks [NN, NN+64*CCH) =
// incremental column-chunk minima (64 cols x 4 row-subchunks per block).
__global__ void k_round(const float* __restrict__ C, const int* __restrict__ rm,
                        const int* __restrict__ cm, u64* __restrict__ rowbest,
                        u64* __restrict__ colpart) {
  __shared__ u64 red[256];
  __shared__ u64 part[4][64];
  int b = blockIdx.x;
  int t = threadIdx.x;
  if (b < NN) {
    int i = b;
    if (rm[i] != -1) return;
    u64 e = rowbest[i];
    u32 jb = (u32)e;
    if (jb < NN && cm[jb] == -1) return;   // cached min col still free -> still the min
    const float* Ci = C + (size_t)i * NN;
    u64 best = ~0ull;
    for (int j0 = t * 4; j0 < NN; j0 += 1024) {
      float4 v = *(const float4*)(Ci + j0);
      int4 m = *(const int4*)(cm + j0);
      const float* vp = (const float*)&v;
      const int* mp = (const int*)&m;
#pragma unroll
      for (int c = 0; c < 4; ++c) {
        if (mp[c] == -1) {
          u64 key = pk(vp[c], (u32)(j0 + c));
          if (key < best) best = key;
        }
      }
    }
    red[t] = best;
    __syncthreads();
    for (int s = 128; s > 0; s >>= 1) {
      if (t < s) { if (red[t + s] < red[t]) red[t] = red[t + s]; }
      __syncthreads();
    }
    if (t == 0) rowbest[i] = red[0];
  } else {
    int idx = b - NN;
    int cb = idx & 63, g = idx >> 6;
    int lane = t & 63, s = t >> 6;
    int j = cb * 64 + lane;
    u64* slot = colpart + (size_t)g * NN + j;
    bool stale = false;
    if (cm[j] == -1) {
      u64 e = *slot;
      if (e != EMPTY) {                    // EMPTY: no free rows; rows never un-match
        u32 io = (u32)e;
        stale = !(io < NN && rm[io] == -1);
      }
    }
    u64 best = ~0ull;
    if (stale) {
      int i0 = g * 256 + s * 64;
      for (int i = i0; i < i0 + 64; ++i) {
        if (rm[i] != -1) continue;
        u64 key = pk(C[(size_t)i * NN + j], (u32)i);
        if (key < best) best = key;
      }
    }
    part[s][lane] = best;
    __syncthreads();
    if (s == 0 && stale) {
      u64 b0 = part[0][lane];
#pragma unroll
      for (int q = 1; q < 4; ++q) if (part[q][lane] < b0) b0 = part[q][lane];
      *slot = b0;
    }
  }
}

__global__ void k_accept3(const u64* __restrict__ colpart, const u64* __restrict__ rowbest,
                          int* rm, int* cm, int* Fcnt) {
  if (*Fcnt == 0) return;
  int j = blockIdx.x * 256 + threadIdx.x;
  if (cm[j] != -1) return;
  u64 best = ~0ull;
#pragma unroll
  for (int g = 0; g < CCH; ++g) {
    u64 v = colpart[(size_t)g * NN + j];
    if (v < best) best = v;
  }
  if (best == ~0ull) return;
  int i = (int)(u32)best;
  if ((u32)(rowbest[i] & 0xffffffffu) == (u32)j) {
    rm[i] = j; cm[j] = i;
    atomicSub(Fcnt, 1);
  }
}

// Endgame: compact free set; if F<=TMAX run exact greedy on static-LDS submatrix
// with per-row cached minima; else global sequential fallback. Exact greedy order
// preserved via key (cost<<24)|(i*NN+j) (i*NN+j fits exactly in 24 bits).
// All loops bounded: each iteration matches exactly one pair.
__global__ __launch_bounds__(256) void k_endgame(const float* __restrict__ C,
                                                 int* rm, int* cm, int* FRg) {
  __shared__ float Csub[TMAX * TMAX];       // 50176 B static
  __shared__ int sF, sG, sc_star, scnt;
  __shared__ int sFR[TMAX], sFC[TMAX];
  __shared__ u64 rkey[TMAX];
  __shared__ int rcol[TMAX];
  __shared__ int cfree[TMAX];
  __shared__ u64 wred[4];
  __shared__ u64 red[256];
  int t = threadIdx.x;
  if (t == 0) { sF = 0; sG = 0; }
  __syncthreads();
  for (int i = t; i < NN; i += 256)
    if (rm[i] == -1) { int p = atomicAdd(&sF, 1); if (p < TMAX) sFR[p] = i; }
  for (int j = t; j < NN; j += 256)
    if (cm[j] == -1) { int p = atomicAdd(&sG, 1); if (p < TMAX) sFC[p] = j; }
  __syncthreads();
  int F = sF;
  if (F == 0) return;
  if (F <= TMAX) {
    for (int r = (t >> 6); r < F; r += 4) {
      const float* Ci = C + (size_t)sFR[r] * NN;
      for (int c = (t & 63); c < F; c += 64) Csub[r * F + c] = Ci[sFC[c]];
    }
    for (int c = t; c < F; c += 256) cfree[c] = 1;
    __syncthreads();
    for (int r = t; r < F; r += 256) {
      const float* row = Csub + r * F;
      u64 bk = ~0ull; int bc = 0; int ig = sFR[r];
      for (int c = 0; c < F; ++c) {
        u64 k = (((u64)__float_as_uint(row[c])) << 24) | (u32)(ig * NN + sFC[c]);
        if (k < bk) { bk = k; bc = c; }
      }
      rkey[r] = bk; rcol[r] = bc;
    }
    __syncthreads();
    for (int it = 0; it < F; ++it) {
      u64 kb = ~0ull;
      if (t < F && rkey[t] != ~0ull) kb = (rkey[t] << 8) | (u64)(u32)t;
      for (int s = 32; s > 0; s >>= 1) {
        u64 o = __shfl_down(kb, s, 64);
        if (o < kb) kb = o;
      }
      if ((t & 63) == 0) wred[t >> 6] = kb;
      __syncthreads();
      if (t == 0) {
        u64 b = wred[0];
#pragma unroll
        for (int wv = 1; wv < 4; ++wv) if (wred[wv] < b) b = wred[wv];
        int rstar = (int)(b & 255);
        if (rstar >= F) rstar = 0;            // defensive clamp (unreachable)
        int cstar = rcol[rstar];
        sc_star = cstar;
        int i = sFR[rstar], j = sFC[cstar];
        rm[i] = j; cm[j] = i;
        rkey[rstar] = ~0ull; cfree[cstar] = 0;
      }
      __syncthreads();
      int cs = sc_star;
      for (int r = t; r < F; r += 256) {
        if (rkey[r] != ~0ull && rcol[r] == cs) {
          const float* row = Csub + r * F;
          u64 bk = ~0ull; int bc = 0; int ig = sFR[r];
          for (int c = 0; c < F; ++c) {
            if (!cfree[c]) continue;
            u64 k = (((u64)__float_as_uint(row[c])) << 24) | (u32)(ig * NN + sFC[c]);
            if (k < bk) { bk = k; bc = c; }
          }
          rkey[r] = bk; rcol[r] = bc;
        }
      }
      __syncthreads();
    }
  } else {
    for (int it = 0; it < NN; ++it) {       // bounded: one match per iteration
      if (t == 0) scnt = 0;
      __syncthreads();
      for (int i = t; i < NN; i += 256)
        if (rm[i] == -1) { int p = atomicAdd(&scnt, 1); FRg[p] = i; }
      __syncthreads();
      int Fa = scnt;
      if (Fa == 0) break;
      u64 best = ~0ull;
      int total = Fa * NN;
      for (int idx = t; idx < total; idx += 256) {
        int b = idx >> 12, j = idx & 4095;
        if (cm[j] != -1) continue;
        int i = FRg[b];
        u64 key = pk(C[(size_t)i * NN + j], (u32)(i * NN + j));
        if (key < best) best = key;
      }
      red[t] = best;
      __syncthreads();
      for (int s = 128; s > 0; s >>= 1) {
        if (t < s) { if (red[t + s] < red[t]) red[t] = red[t + s]; }
        __syncthreads();
      }
      if (t == 0) {
        u32 lo = (u32)red[0];
        rm[lo >> 12] = lo & 4095; cm[lo & 4095] = lo >> 12;
      }
      __syncthreads();
    }
  }
}

// ---------- fallback path (no C in workspace) — unchanged, proven ----------
template <bool USEC>
__global__ void k_rowpass(const float* __restrict__ C,
                          const float* __restrict__ x, const float* __restrict__ y,
                          const float* __restrict__ xx, const float* __restrict__ yy,
                          const int* __restrict__ cm, const int* __restrict__ FR,
                          const int* __restrict__ Fcnt, u64* __restrict__ rowbest) {
  int b = blockIdx.x;
  if (b >= *Fcnt) return;
  int i = FR[b];
  __shared__ float xsh[DD];
  __shared__ u64 red[256];
  int t = threadIdx.x;
  if (!USEC) { if (t < DD) xsh[t] = x[(size_t)i * DD + t]; }
  __syncthreads();
  float xxi = xx[i];
  u64 best = ~0ull;
  for (int j = t; j < NN; j += 256) {
    if (cm[j] != -1) continue;
    float d;
    if (USEC) {
      d = C[(size_t)i * NN + j];
    } else {
      const float* yj = y + (size_t)j * DD;
      float dot = 0.f;
#pragma unroll
      for (int k = 0; k < DD; ++k) dot = fmaf(xsh[k], yj[k], dot);
      float sq = (xxi + yy[j]) - 2.0f * dot;
      d = sqrtf(fmaxf(sq, 0.f));
    }
    u64 key = pk(d, (u32)j);
    if (key < best) best = key;
  }
  red[t] = best;
  __syncthreads();
  for (int s = 128; s > 0; s >>= 1) {
    if (t < s) { if (red[t + s] < red[t]) red[t] = red[t + s]; }
    __syncthreads();
  }
  if (t == 0) rowbest[i] = red[0];
}

template <bool USEC>
__global__ void k_colpass(const float* __restrict__ C,
                          const float* __restrict__ x, const float* __restrict__ y,
                          const float* __restrict__ xx, const float* __restrict__ yy,
                          const int* __restrict__ cm, const int* __restrict__ FR,
                          const int* __restrict__ Fcnt, u64* __restrict__ colpart) {
  int t = threadIdx.x;
  int j = blockIdx.x * 256 + t;
  int g = blockIdx.y;
  int F = *Fcnt;
  if (F == 0) return;
  int b0 = (g * F) / GCOL, b1 = ((g + 1) * F) / GCOL;
  u64 best = ~0ull;
  if (cm[j] == -1) {
    float yyj = yy[j];
    if (USEC) {
      for (int b = b0; b < b1; ++b) {
        int i = FR[b];
        u64 key = pk(C[(size_t)i * NN + j], (u32)i);
        if (key < best) best = key;
      }
    } else {
      float4 yr[16];
      const float4* yj4 = (const float4*)(y + (size_t)j * DD);
#pragma unroll
      for (int q = 0; q < 16; ++q) yr[q] = yj4[q];
      for (int b = b0; b < b1; ++b) {
        int i = FR[b];
        const float4* xi4 = (const float4*)(x + (size_t)i * DD);
        float dot = 0.f;
#pragma unroll
        for (int q = 0; q < 16; ++q) {
          float4 a = xi4[q], bb = yr[q];
          dot = fmaf(a.x, bb.x, dot); dot = fmaf(a.y, bb.y, dot);
          dot = fmaf(a.z, bb.z, dot); dot = fmaf(a.w, bb.w, dot);
        }
        float sq = (xx[i] + yyj) - 2.0f * dot;
        float d = sqrtf(fmaxf(sq, 0.f));
        u64 key = pk(d, (u32)i);
        if (key < best) best = key;
      }
    }
  }
  colpart[(size_t)g * NN + j] = best;
}

__global__ void k_accept(const u64* __restrict__ colpart, const u64* __restrict__ rowbest,
                         int* rm, int* cm, int* FR, int* Fcnt) {
  __shared__ int scnt;
  int t = threadIdx.x;
  if (*Fcnt == 0) return;
  for (int j = t; j < NN; j += 1024) {
    if (cm[j] != -1) continue;
    u64 best = ~0ull;
#pragma unroll
    for (int g = 0; g < GCOL; ++g) {
      u64 v = colpart[(size_t)g * NN + j];
      if (v < best) best = v;
    }
    if (best == ~0ull) continue;
    int i = (int)(u32)best;
    if ((u32)(rowbest[i] & 0xffffffffu) == (u32)j) { rm[i] = j; cm[j] = i; }
  }
  __syncthreads();
  if (t == 0) scnt = 0;
  __syncthreads();
  for (int i = t; i < NN; i += 1024)
    if (rm[i] == -1) { int p = atomicAdd(&scnt, 1); FR[p] = i; }
  __syncthreads();
  if (t == 0) *Fcnt = scnt;
}

template <bool USEC>
__global__ void k_cleanup(const float* __restrict__ C,
                          const float* __restrict__ x, const float* __restrict__ y,
                          const float* __restrict__ xx, const float* __restrict__ yy,
                          int* rm, int* cm, int* FR) {
  __shared__ int scnt;
  __shared__ u64 red[1024];
  int t = threadIdx.x;
  for (int it = 0; it < NN; ++it) {         // bounded: one match per iteration
    if (t == 0) scnt = 0;
    __syncthreads();
    for (int i = t; i < NN; i += 1024)
      if (rm[i] == -1) { int p = atomicAdd(&scnt, 1); FR[p] = i; }
    __syncthreads();
    int F = scnt;
    if (F == 0) break;
    u64 best = ~0ull;
    int total = F * NN;
    for (int idx = t; idx < total; idx += 1024) {
      int b = idx >> 12;
      int j = idx & 4095;
      if (cm[j] != -1) continue;
      int i = FR[b];
      float d;
      if (USEC) d = C[(size_t)i * NN + j];
      else d = distfly(x, y, xx[i], yy[j], i, j);
      u64 key = pk(d, (u32)(i * NN + j));
      if (key < best) best = key;
    }
    red[t] = best;
    __syncthreads();
    for (int s = 512; s > 0; s >>= 1) {
      if (t < s) { if (red[t + s] < red[t]) red[t] = red[t + s]; }
      __syncthreads();
    }
    if (t == 0) {
      u32 lo = (u32)red[0];
      int i = lo >> 12, j = lo & 4095;
      rm[i] = j; cm[j] = i;
    }
    __syncthreads();
  }
}

extern "C" void kernel_launch(void* const* d_in, const int* in_sizes, int n_in,
                              void* d_out, int out_size, void* d_ws, size_t ws_size,
                              hipStream_t stream) {
  const float* x = (const float*)d_in[0];
  const float* y = (const float*)d_in[1];
  int* cm = (int*)d_out;

  char* w = (char*)d_ws;
  float* xx = (float*)(w + 0);
  float* yy = (float*)(w + 16384);
  int* rm = (int*)(w + 32768);
  int* FR = (int*)(w + 49152);
  int* Fcnt = (int*)(w + 65536);
  u64* rowbest = (u64*)(w + 65664);
  u64* colpart = (u64*)(w + 98432);   // 16 x 4096 x 8 = 512 KB, ends 622720
  float* C = (float*)(w + 1048576);

  size_t need = 1048576 + (size_t)NN * NN * 4;
  bool usec = ws_size >= need;

  k_init<<<dim3(16), 256, 0, stream>>>(x, y, xx, yy, rm, cm, FR, Fcnt, rowbest, colpart);
  if (usec) {
    k_build<<<dim3(64, 64), 256, 0, stream>>>(x, y, xx, yy, C);
    for (int r = 0; r < ROUNDS_FAST; ++r) {
      k_round<<<dim3(NN + 64 * CCH), 256, 0, stream>>>(C, rm, cm, rowbest, colpart);
      k_accept3<<<dim3(16), 256, 0, stream>>>(colpart, rowbest, rm, cm, Fcnt);
    }
    k_endgame<<<dim3(1), 256, 0, stream>>>(C, rm, cm, FR);
  } else {
    for (int r = 0; r < ROUNDS_FB; ++r) {
      k_rowpass<false><<<dim3(NN), 256, 0, stream>>>(nullptr, x, y, xx, yy, cm, FR, Fcnt, rowbest);
      k_colpass<false><<<dim3(16, GCOL), 256, 0, stream>>>(nullptr, x, y, xx, yy, cm, FR, Fcnt, colpart);
      k_accept<<<dim3(1), 1024, 0, stream>>>(colpart, rowbest, rm, cm, FR, Fcnt);
    }
    k_cleanup<false><<<dim3(1), 1024, 0, stream>>>(nullptr, x, y, xx, yy, rm, cm, FR);
  }
}